// Round 2
// baseline (3320.964 us; speedup 1.0000x reference)
//
#include <hip/hip_runtime.h>
#include <math.h>

#define DEVI __device__ __forceinline__

DEVI float silu_f(float x){ return x / (1.0f + __expf(-x)); }

// ---------------- utility: zero a float region ----------------
__global__ void k_zero(float* p, int n){
  int i = blockIdx.x*256 + threadIdx.x;
  if (i < n) p[i] = 0.f;
}

// ---------------- weight transforms ----------------
// conv: OIHW [CO][CI][3][3] -> K-major [CI*9][CO]
// deconv: [CI=128][CO=3][4][4] -> [tap=ky*4+kx][ci][co] flat
struct XJob { const float* src; float* dst; int ci, co, n, deconv; };
struct XArgs { XJob j[10]; };

__global__ void k_xform(XArgs a){
  XJob jb = a.j[blockIdx.y];
  int e = blockIdx.x*256 + threadIdx.x;
  if (e >= jb.n) return;
  if (!jb.deconv){
    int co = e % jb.co; int k = e / jb.co; int ci = k/9; int jj = k - ci*9;
    jb.dst[e] = jb.src[(co*jb.ci + ci)*9 + jj];
  } else {
    int co = e % 3; int r = e/3; int ci = r & 127; int tap = r >> 7;
    int ky = tap >> 2, kx = tap & 3;
    jb.dst[e] = jb.src[((ci*3 + co)*4 + ky)*4 + kx];
  }
}

// ---------------- conv 3x3, CIN=3, NCHW input -> NHWC output, silu ----------------
template<int CO>
__global__ __launch_bounds__(256)
void k_conv_cin3(const float* __restrict__ x, const float* __restrict__ wt,
                 const float* __restrict__ bias, float* __restrict__ out){
  constexpr int CO4 = CO/4;
  constexpr int PPB = 256/CO4;
  int t = threadIdx.x;
  int co4 = t % CO4, pi = t / CO4;
  int p = blockIdx.x*PPB + pi;
  int b = p >> 16;
  int rem = p & 65535;
  int y = rem >> 8, xx = rem & 255;
  float4 acc = *(const float4*)(bias + co4*4);
  #pragma unroll
  for (int ci = 0; ci < 3; ++ci)
    for (int dy = 0; dy < 3; ++dy){
      int yy = y + dy - 1;
      if ((unsigned)yy >= 256u) continue;
      for (int dx = 0; dx < 3; ++dx){
        int xg = xx + dx - 1;
        if ((unsigned)xg >= 256u) continue;
        float v = x[(((size_t)b*3 + ci)*256 + yy)*256 + xg];
        int k = ci*9 + dy*3 + dx;
        float4 w = *(const float4*)(wt + (size_t)k*CO + co4*4);
        acc.x += v*w.x; acc.y += v*w.y; acc.z += v*w.z; acc.w += v*w.w;
      }
    }
  float4 o; o.x = silu_f(acc.x); o.y = silu_f(acc.y); o.z = silu_f(acc.z); o.w = silu_f(acc.w);
  *(float4*)(out + (size_t)p*CO + co4*4) = o;
}

// ---------------- generic 3x3 row conv, NHWC, silu, optional per-channel scale/shift on input ----------------
template<int CIN, int CO, int STRIDE, int PXB>
__global__ __launch_bounds__(256)
void k_rowconv(const float* __restrict__ in, const float* __restrict__ wt,
               const float* __restrict__ bias, float* __restrict__ out,
               const float* __restrict__ sc, const float* __restrict__ sh,
               int H_in, int W_in){
  constexpr int WT = PXB*STRIDE + 2;
  constexpr int CO8 = CO/8;
  constexpr int PG = 256/CO8;
  constexpr int PPT = PXB/PG;
  constexpr int SEGS = 128/PXB;
  __shared__ float lds[WT*CIN];
  __shared__ float scl[CIN], shl[CIN];
  int t = threadIdx.x;
  int co8 = t % CO8, pg = t / CO8;
  int blk = blockIdx.x;
  int seg = blk % SEGS; int oy = (blk/SEGS) & 127; int b = blk/(SEGS*128);
  int x0 = seg*PXB;
  bool hasS = (sc != nullptr);
  if (hasS && t < CIN){ scl[t] = sc[t]; shl[t] = sh[t]; }
  __syncthreads();
  float acc[PPT][8];
  {
    float4 b0 = *(const float4*)(bias + co8*8);
    float4 b1 = *(const float4*)(bias + co8*8 + 4);
    #pragma unroll
    for (int i=0;i<PPT;i++){
      acc[i][0]=b0.x; acc[i][1]=b0.y; acc[i][2]=b0.z; acc[i][3]=b0.w;
      acc[i][4]=b1.x; acc[i][5]=b1.y; acc[i][6]=b1.z; acc[i][7]=b1.w;
    }
  }
  const int gx0 = x0*STRIDE - 1;
  for (int dy=0; dy<3; ++dy){
    int iy = oy*STRIDE + dy - 1;
    if ((unsigned)iy < (unsigned)H_in){
      const float* rowp = in + ((size_t)b*H_in + iy)*(size_t)W_in*CIN;
      for (int i = t; i < WT*(CIN/4); i += 256){
        int col = i / (CIN/4); int cq = i % (CIN/4);
        int gx = gx0 + col;
        float4 v = make_float4(0.f,0.f,0.f,0.f);
        if ((unsigned)gx < (unsigned)W_in){
          v = *(const float4*)(rowp + (size_t)gx*CIN + cq*4);
          if (hasS){
            v.x = v.x*scl[cq*4+0] + shl[cq*4+0];
            v.y = v.y*scl[cq*4+1] + shl[cq*4+1];
            v.z = v.z*scl[cq*4+2] + shl[cq*4+2];
            v.w = v.w*scl[cq*4+3] + shl[cq*4+3];
          }
        }
        *(float4*)(&lds[col*CIN + cq*4]) = v;
      }
      __syncthreads();
      for (int dx=0; dx<3; ++dx){
        for (int cq=0; cq<CIN/4; ++cq){
          float4 a4[PPT];
          #pragma unroll
          for (int i=0;i<PPT;i++){
            int lx = (pg*PPT + i)*STRIDE + dx;
            a4[i] = *(const float4*)(&lds[lx*CIN + cq*4]);
          }
          const float* wk = wt + ((size_t)(cq*4)*9 + dy*3 + dx)*CO + co8*8;
          #pragma unroll
          for (int cc=0; cc<4; ++cc){
            float4 w0 = *(const float4*)(wk + (size_t)cc*9*CO);
            float4 w1 = *(const float4*)(wk + (size_t)cc*9*CO + 4);
            #pragma unroll
            for (int i=0;i<PPT;i++){
              float av = (cc==0) ? a4[i].x : (cc==1) ? a4[i].y : (cc==2) ? a4[i].z : a4[i].w;
              acc[i][0] += av*w0.x; acc[i][1] += av*w0.y; acc[i][2] += av*w0.z; acc[i][3] += av*w0.w;
              acc[i][4] += av*w1.x; acc[i][5] += av*w1.y; acc[i][6] += av*w1.z; acc[i][7] += av*w1.w;
            }
          }
        }
      }
      __syncthreads();
    }
  }
  #pragma unroll
  for (int i=0;i<PPT;i++){
    int px = x0 + pg*PPT + i;
    float4 o0, o1;
    o0.x = silu_f(acc[i][0]); o0.y = silu_f(acc[i][1]); o0.z = silu_f(acc[i][2]); o0.w = silu_f(acc[i][3]);
    o1.x = silu_f(acc[i][4]); o1.y = silu_f(acc[i][5]); o1.z = silu_f(acc[i][6]); o1.w = silu_f(acc[i][7]);
    float* op = out + (((size_t)b*128 + oy)*128 + px)*CO + co8*8;
    *(float4*)op = o0; *(float4*)(op+4) = o1;
  }
}

// ---------------- memcell weights: w[t][m] = softmax_m(TAU*(2 z.zhat - |zhat|^2)), stored transposed [M][T] ----------------
__global__ __launch_bounds__(256)
void k_weights(const float* __restrict__ z, const float* __restrict__ zhat,
               float* __restrict__ wT, const float* __restrict__ sc,
               const float* __restrict__ sh, int T){
  __shared__ float zl[128*16];
  __shared__ float zn[128];
  __shared__ float scl[16], shl[16];
  int t = threadIdx.x;
  if (t < 128){
    float s2 = 0.f;
    #pragma unroll
    for (int j=0;j<16;j++){ float v = zhat[t*16+j]; zl[t*16+j] = v; s2 += v*v; }
    zn[t] = s2;
  }
  if (t < 16){ scl[t] = sc ? sc[t] : 1.f; shl[t] = sh ? sh[t] : 0.f; }
  __syncthreads();
  size_t tok = (size_t)blockIdx.x*256 + t;
  float zr[16];
  #pragma unroll
  for (int q=0;q<4;q++){
    float4 v = *(const float4*)(z + tok*16 + q*4);
    zr[q*4+0] = v.x*scl[q*4+0]+shl[q*4+0];
    zr[q*4+1] = v.y*scl[q*4+1]+shl[q*4+1];
    zr[q*4+2] = v.z*scl[q*4+2]+shl[q*4+2];
    zr[q*4+3] = v.w*scl[q*4+3]+shl[q*4+3];
  }
  float mx = -1e30f;
  for (int m=0;m<128;m++){
    float d=0.f;
    #pragma unroll
    for (int j=0;j<16;j++) d += zr[j]*zl[m*16+j];
    float s = 5.0f*(2.f*d - zn[m]);
    mx = fmaxf(mx, s);
  }
  float sum=0.f;
  for (int m=0;m<128;m++){
    float d=0.f;
    #pragma unroll
    for (int j=0;j<16;j++) d += zr[j]*zl[m*16+j];
    sum += __expf(5.0f*(2.f*d - zn[m]) - mx);
  }
  float inv = 1.f/sum;
  for (int m=0;m<128;m++){
    float d=0.f;
    #pragma unroll
    for (int j=0;j<16;j++) d += zr[j]*zl[m*16+j];
    wT[(size_t)m*T + tok] = __expf(5.0f*(2.f*d - zn[m]) - mx)*inv;
  }
}

// ---------------- out[t][s] = (add? addsrc : 0) + sum_m wT[m][t]*(mat1+mat2)[m][s]; opt tanh; opt bn-stats (f64 global accum) ----------------
template<int S, bool ADD, bool DOTANH, bool STATS, bool MAT2>
__global__ __launch_bounds__(256)
void k_gemm_out(const float* __restrict__ wT, const float* __restrict__ mat1,
                const float* __restrict__ mat2, const float* __restrict__ addsrc,
                float* __restrict__ dst, double* __restrict__ stats, int T){
  constexpr int TOKB = (S==128)?64:128;
  __shared__ float ml[128*S];
  __shared__ float ssum[S], ssq[S];
  int t = threadIdx.x;
  if (STATS && t < S){ ssum[t]=0.f; ssq[t]=0.f; }
  for (int i=t; i < 128*S/4; i += 256){
    float4 v = ((const float4*)mat1)[i];
    if (MAT2){ float4 u = ((const float4*)mat2)[i]; v.x+=u.x; v.y+=u.y; v.z+=u.z; v.w+=u.w; }
    ((float4*)ml)[i] = v;
  }
  __syncthreads();
  size_t tb = (size_t)blockIdx.x*TOKB;
  if constexpr (S==128){
    int s8 = t & 15, tg = t >> 4;
    float acc[4][8];
    #pragma unroll
    for (int i=0;i<4;i++) for (int j=0;j<8;j++) acc[i][j]=0.f;
    for (int m=0;m<128;m++){
      float4 wv = *(const float4*)(wT + (size_t)m*T + tb + tg*4);
      float4 c0 = *(const float4*)(&ml[m*128 + s8*8]);
      float4 c1 = *(const float4*)(&ml[m*128 + s8*8 + 4]);
      float c[8] = {c0.x,c0.y,c0.z,c0.w,c1.x,c1.y,c1.z,c1.w};
      float w[4] = {wv.x,wv.y,wv.z,wv.w};
      #pragma unroll
      for (int i=0;i<4;i++)
        #pragma unroll
        for (int j=0;j<8;j++) acc[i][j] += w[i]*c[j];
    }
    float ls[8], lq[8];
    #pragma unroll
    for (int j=0;j<8;j++){ ls[j]=0.f; lq[j]=0.f; }
    #pragma unroll
    for (int i=0;i<4;i++){
      size_t tok = tb + tg*4 + i;
      float o[8];
      #pragma unroll
      for (int j=0;j<8;j++) o[j]=acc[i][j];
      if (ADD){
        float4 a0 = *(const float4*)(addsrc + tok*128 + s8*8);
        float4 a1 = *(const float4*)(addsrc + tok*128 + s8*8+4);
        o[0]+=a0.x; o[1]+=a0.y; o[2]+=a0.z; o[3]+=a0.w;
        o[4]+=a1.x; o[5]+=a1.y; o[6]+=a1.z; o[7]+=a1.w;
      }
      if (DOTANH){
        #pragma unroll
        for (int j=0;j<8;j++) o[j]=tanhf(o[j]);
      }
      float4 r0 = {o[0],o[1],o[2],o[3]}, r1 = {o[4],o[5],o[6],o[7]};
      *(float4*)(dst + tok*128 + s8*8) = r0;
      *(float4*)(dst + tok*128 + s8*8 + 4) = r1;
      if (STATS){
        #pragma unroll
        for (int j=0;j<8;j++){ ls[j]+=o[j]; lq[j]+=o[j]*o[j]; }
      }
    }
    if (STATS){
      #pragma unroll
      for (int j=0;j<8;j++){ atomicAdd(&ssum[s8*8+j], ls[j]); atomicAdd(&ssq[s8*8+j], lq[j]); }
      __syncthreads();
      if (t < 128){
        atomicAdd(&stats[t], (double)ssum[t]);
        atomicAdd(&stats[128+t], (double)ssq[t]);
      }
    }
  } else {
    int s8 = t & 1, tg = t >> 1;
    float acc[8];
    #pragma unroll
    for (int j=0;j<8;j++) acc[j]=0.f;
    size_t tok = tb + tg;
    for (int m=0;m<128;m++){
      float wv = wT[(size_t)m*T + tok];
      float4 c0 = *(const float4*)(&ml[m*16 + s8*8]);
      float4 c1 = *(const float4*)(&ml[m*16 + s8*8 + 4]);
      acc[0]+=wv*c0.x; acc[1]+=wv*c0.y; acc[2]+=wv*c0.z; acc[3]+=wv*c0.w;
      acc[4]+=wv*c1.x; acc[5]+=wv*c1.y; acc[6]+=wv*c1.z; acc[7]+=wv*c1.w;
    }
    float o[8];
    #pragma unroll
    for (int j=0;j<8;j++) o[j]=acc[j];
    if (ADD){
      float4 a0 = *(const float4*)(addsrc + tok*16 + s8*8);
      float4 a1 = *(const float4*)(addsrc + tok*16 + s8*8+4);
      o[0]+=a0.x; o[1]+=a0.y; o[2]+=a0.z; o[3]+=a0.w;
      o[4]+=a1.x; o[5]+=a1.y; o[6]+=a1.z; o[7]+=a1.w;
    }
    if (DOTANH){
      #pragma unroll
      for (int j=0;j<8;j++) o[j]=tanhf(o[j]);
    }
    float4 r0 = {o[0],o[1],o[2],o[3]}, r1 = {o[4],o[5],o[6],o[7]};
    *(float4*)(dst + tok*16 + s8*8) = r0;
    *(float4*)(dst + tok*16 + s8*8 + 4) = r1;
    if (STATS){
      #pragma unroll
      for (int j=0;j<8;j++){ atomicAdd(&ssum[s8*8+j], o[j]); atomicAdd(&ssq[s8*8+j], o[j]*o[j]); }
      __syncthreads();
      if (t < 16){
        atomicAdd(&stats[t], (double)ssum[t]);
        atomicAdd(&stats[16+t], (double)ssq[t]);
      }
    }
  }
}

// ---------------- delta[m][s] += sum_t wT[m][t] * ALPHA*(Tstar - read)[t][s]  (split-K, atomic) ----------------
template<int S>
__global__ __launch_bounds__(256)
void k_delta(const float* __restrict__ wT, const float* __restrict__ tstar,
             const float* __restrict__ rd, float* __restrict__ delta, int T, int KCH){
  constexpr int SUB = 64;
  constexpr int SJ = (S==128)?8:1;
  __shared__ float wl[128*SUB];
  __shared__ float dl[SUB*S];
  int t = threadIdx.x;
  int tm = t >> 4, ts = t & 15;
  size_t base = (size_t)blockIdx.x * KCH;
  float acc[8][SJ];
  #pragma unroll
  for (int i=0;i<8;i++) for (int j=0;j<SJ;j++) acc[i][j]=0.f;
  for (int c0=0; c0<KCH; c0+=SUB){
    for (int i=t; i<128*SUB/4; i+=256){
      int m = i >> 4; int tq = i & 15;
      float4 v = *(const float4*)(wT + (size_t)m*T + base + c0 + tq*4);
      *(float4*)(&wl[m*SUB + tq*4]) = v;
    }
    for (int i=t; i<SUB*S/4; i+=256){
      int tt = i/(S/4); int sq = i%(S/4);
      size_t tok = base + c0 + tt;
      float4 a = *(const float4*)(tstar + tok*S + sq*4);
      float4 r = *(const float4*)(rd + tok*S + sq*4);
      float4 d; d.x = 0.1f*(a.x-r.x); d.y = 0.1f*(a.y-r.y); d.z = 0.1f*(a.z-r.z); d.w = 0.1f*(a.w-r.w);
      *(float4*)(&dl[tt*S + sq*4]) = d;
    }
    __syncthreads();
    for (int tt=0; tt<SUB; ++tt){
      float wv[8];
      #pragma unroll
      for (int i=0;i<8;i++) wv[i] = wl[(tm*8+i)*SUB + tt];
      if constexpr (S==128){
        float4 d0 = *(const float4*)(&dl[tt*128 + ts*8]);
        float4 d1 = *(const float4*)(&dl[tt*128 + ts*8 + 4]);
        float d[8] = {d0.x,d0.y,d0.z,d0.w,d1.x,d1.y,d1.z,d1.w};
        #pragma unroll
        for (int i=0;i<8;i++)
          #pragma unroll
          for (int j=0;j<8;j++) acc[i][j] += wv[i]*d[j];
      } else {
        float d = dl[tt*16 + ts];
        #pragma unroll
        for (int i=0;i<8;i++) acc[i][0] += wv[i]*d;
      }
    }
    __syncthreads();
  }
  if constexpr (S==128){
    #pragma unroll
    for (int i=0;i<8;i++)
      for (int j=0;j<8;j++)
        atomicAdd(&delta[(tm*8+i)*128 + ts*8 + j], acc[i][j]);
  } else {
    #pragma unroll
    for (int i=0;i<8;i++)
      atomicAdd(&delta[(tm*8+i)*16 + ts], acc[i][0]);
  }
}

// ---------------- BN finalize: per-channel scale/shift (f64 stats) ----------------
__global__ void k_bnfin(const double* __restrict__ stats, const float* __restrict__ g,
                        const float* __restrict__ b, float* __restrict__ sc,
                        float* __restrict__ sh, int C, double invT){
  int c = threadIdx.x; if (c >= C) return;
  double mean = stats[c]*invT;
  double var = stats[C+c]*invT - mean*mean;
  if (var < 0.0) var = 0.0;
  double s = (double)g[c] / sqrt(var + 1e-5);
  sc[c] = (float)s; sh[c] = (float)((double)b[c] - mean*s);
}

// ---------------- deconv 4x4 stride2 pad1, CIN=128 NHWC(+bn) -> CO=3 NHWC, silu ----------------
__global__ __launch_bounds__(256)
void k_deconv(const float* __restrict__ in, const float* __restrict__ wd,
              const float* __restrict__ bias, float* __restrict__ out,
              const float* __restrict__ sc, const float* __restrict__ sh){
  __shared__ float lds[2*130*128];
  __shared__ float scl[128], shl[128];
  int t = threadIdx.x;
  int oy = blockIdx.x & 255; int b = blockIdx.x >> 8;
  if (t < 128){ scl[t]=sc[t]; shl[t]=sh[t]; }
  __syncthreads();
  int p = (oy+1)&1;
  int iy_hi = (oy+1-p)>>1;
  for (int r=0;r<2;r++){
    int iy = iy_hi - 1 + r;
    bool valid = (unsigned)iy < 128u;
    const float* rp = in + ((size_t)b*128 + iy)*128*128;
    for (int i=t; i<130*32; i+=256){
      int col=i/32, cq=i%32;
      int ix = col-1;
      float4 v = make_float4(0.f,0.f,0.f,0.f);
      if (valid && (unsigned)ix<128u){
        v = *(const float4*)(rp + (size_t)ix*128 + cq*4);
        v.x = v.x*scl[cq*4+0]+shl[cq*4+0];
        v.y = v.y*scl[cq*4+1]+shl[cq*4+1];
        v.z = v.z*scl[cq*4+2]+shl[cq*4+2];
        v.w = v.w*scl[cq*4+3]+shl[cq*4+3];
      }
      *(float4*)(&lds[(r*130+col)*128 + cq*4]) = v;
    }
  }
  __syncthreads();
  int ox = t;
  int px_ = (ox+1)&1;
  int ix_hi = (ox+1-px_)>>1;
  float acc0=bias[0], acc1=bias[1], acc2=bias[2];
  for (int ry=0; ry<2; ++ry){
    for (int cx=0; cx<2; ++cx){
      int kx = px_ + 2*(1-cx);
      int ix = ix_hi - (1-cx);
      int lcol = ix + 1;
      int ky = p + 2*(1-ry);
      int tap = ky*4 + kx;
      const float* lp = &lds[(ry*130 + lcol)*128];
      const float* wp = wd + (size_t)tap*128*3;
      for (int cq=0; cq<32; ++cq){
        float4 a = *(const float4*)(lp + cq*4);
        float4 w0 = *(const float4*)(wp + cq*12);
        float4 w1 = *(const float4*)(wp + cq*12+4);
        float4 w2 = *(const float4*)(wp + cq*12+8);
        acc0 += a.x*w0.x + a.y*w0.w + a.z*w1.z + a.w*w2.y;
        acc1 += a.x*w0.y + a.y*w1.x + a.z*w1.w + a.w*w2.z;
        acc2 += a.x*w0.z + a.y*w1.y + a.z*w2.x + a.w*w2.w;
      }
    }
  }
  float* op = out + (((size_t)b*256 + oy)*256 + ox)*3;
  op[0]=silu_f(acc0); op[1]=silu_f(acc1); op[2]=silu_f(acc2);
}

// ---------------- final conv 3x3, 3->3, NHWC in -> NCHW out, silu ----------------
__global__ __launch_bounds__(256)
void k_conv33(const float* __restrict__ in, const float* __restrict__ wt,
              const float* __restrict__ bias, float* __restrict__ out){
  int pidx = blockIdx.x*256 + threadIdx.x;
  int b = pidx >> 16; int rem = pidx & 65535;
  int y = rem >> 8, x = rem & 255;
  float a0=bias[0], a1=bias[1], a2=bias[2];
  for (int dy=0;dy<3;dy++){
    int yy=y+dy-1; if((unsigned)yy>=256u) continue;
    for (int dx=0;dx<3;dx++){
      int xx2=x+dx-1; if((unsigned)xx2>=256u) continue;
      const float* ip = in + (((size_t)b*256+yy)*256+xx2)*3;
      #pragma unroll
      for (int ci=0;ci<3;ci++){
        float v = ip[ci];
        const float* wp = wt + (ci*9 + dy*3 + dx)*3;
        a0 += v*wp[0]; a1 += v*wp[1]; a2 += v*wp[2];
      }
    }
  }
  size_t o = (size_t)b*3*65536 + (size_t)y*256 + x;
  out[o]         = silu_f(a0);
  out[o+65536]   = silu_f(a1);
  out[o+2*65536] = silu_f(a2);
}

// ================= host side =================
extern "C" void kernel_launch(void* const* d_in, const int* in_sizes, int n_in,
                              void* d_out, int out_size, void* d_ws, size_t ws_size,
                              hipStream_t stream) {
  const float* x       = (const float*)d_in[0];
  const float* e0n_w1  = (const float*)d_in[1];
  const float* e0n_b1  = (const float*)d_in[2];
  const float* e0n_w2  = (const float*)d_in[3];
  const float* e0n_b2  = (const float*)d_in[4];
  const float* e0s_w1  = (const float*)d_in[5];
  const float* e0s_b1  = (const float*)d_in[6];
  const float* e0s_w2  = (const float*)d_in[7];
  const float* e0s_b2  = (const float*)d_in[8];
  const float* bnn_w1  = (const float*)d_in[9];
  const float* bnn_b1  = (const float*)d_in[10];
  const float* bnn_w2  = (const float*)d_in[11];
  const float* bnn_b2  = (const float*)d_in[12];
  const float* bns_w1  = (const float*)d_in[13];
  const float* bns_b1  = (const float*)d_in[14];
  const float* bns_w2  = (const float*)d_in[15];
  const float* bns_b2  = (const float*)d_in[16];
  const float* d0_wt   = (const float*)d_in[17];
  const float* d0_bt   = (const float*)d_in[18];
  const float* d0_wc   = (const float*)d_in[19];
  const float* d0_bc   = (const float*)d_in[20];
  const float* g0      = (const float*)d_in[21];
  const float* be0     = (const float*)d_in[22];
  const float* gb      = (const float*)d_in[23];
  const float* bb      = (const float*)d_in[24];
  const float* gd      = (const float*)d_in[25];
  const float* bd      = (const float*)d_in[26];
  const float* c0_zhat = (const float*)d_in[27];
  const float* c0_That = (const float*)d_in[28];
  const float* cb_zhat = (const float*)d_in[29];
  const float* cb_That = (const float*)d_in[30];

  char* wsb = (char*)d_ws;
  const size_t SLOT = 33554432ull;
  const size_t R1 = 4*SLOT;                 // 134217728
  const size_t R2 = R1 + 16777216ull;       // 150994944
  const size_t R3 = R2 + 4194304ull;        // 155189248
  const size_t R4 = R3 + 33554432ull;       // 188743680
  const size_t WB = R4 + 81920ull;
  const size_t NEED = WB + 1967104ull;      // 190792704
  if (ws_size < NEED) return;

  float* t1    = (float*)(wsb + 0);
  float* w0T   = (float*)(wsb + 0);
  float* u2    = (float*)(wsb + 0);
  float* xt3   = (float*)(wsb + 0);
  float* read0 = (float*)(wsb + SLOT);
  float* w2T   = (float*)(wsb + SLOT);
  float* xt1   = (float*)(wsb + 2*SLOT);
  float* wbT   = (float*)(wsb + 2*SLOT);
  float* u1    = (float*)(wsb + 3*SLOT);
  float* t0    = (float*)(wsb + R1);
  float* bnnb  = (float*)(wsb + R1);
  float* bnsb  = (float*)(wsb + R1 + 4194304ull);
  float* readb = (float*)(wsb + R1 + 8388608ull);
  float* xt2   = (float*)(wsb + R1 + 12582912ull);
  float* e0n   = (float*)(wsb + R2);
  float* y1    = (float*)(wsb + R2);
  float* e0s   = (float*)(wsb + R3);
  float* delta0 = (float*)(wsb + R4);                     // 65536 B
  float* deltab = (float*)(wsb + R4 + 65536ull);          // 8192 B
  double* stats0 = (double*)(wsb + R4 + 73728ull);        // 2048 B (256 f64)
  double* statsb = (double*)(wsb + R4 + 75776ull);        // 512 B  (32 f64 used)
  double* statsd = (double*)(wsb + R4 + 76288ull);        // 2048 B (256 f64)
  float* sc0 = (float*)(wsb + R4 + 78336ull);
  float* sh0 = (float*)(wsb + R4 + 78848ull);
  float* scb = (float*)(wsb + R4 + 79360ull);
  float* shb = (float*)(wsb + R4 + 79872ull);
  float* scd = (float*)(wsb + R4 + 80384ull);
  float* shd = (float*)(wsb + R4 + 80896ull);
  float* wt_e0n1 = (float*)(wsb + WB);
  float* wt_e0n2 = (float*)(wsb + WB + 2048ull);
  float* wt_e0s1 = (float*)(wsb + WB + 11264ull);
  float* wt_e0s2 = (float*)(wsb + WB + 25088ull);
  float* wt_bnn1 = (float*)(wsb + WB + 614912ull);
  float* wt_bnn2 = (float*)(wsb + WB + 1204736ull);
  float* wt_bns1 = (float*)(wsb + WB + 1278464ull);
  float* wt_bns2 = (float*)(wsb + WB + 1868288ull);
  float* wt_d0c  = (float*)(wsb + WB + 1942016ull);
  float* wd_dec  = (float*)(wsb + WB + 1942528ull);

  const int T = 65536;
  const double invT = 1.0/65536.0;

  // zero deltas + f64 stats region: (78336 bytes => 19584 floats)
  k_zero<<<77, 256, 0, stream>>>((float*)(wsb + R4), 19584);

  // weight transforms (one launch)
  XArgs xa;
  xa.j[0] = { e0n_w1, wt_e0n1, 3, 16, 432, 0 };
  xa.j[1] = { e0n_w2, wt_e0n2, 16, 16, 2304, 0 };
  xa.j[2] = { e0s_w1, wt_e0s1, 3, 128, 3456, 0 };
  xa.j[3] = { e0s_w2, wt_e0s2, 128, 128, 147456, 0 };
  xa.j[4] = { bnn_w1, wt_bnn1, 128, 128, 147456, 0 };
  xa.j[5] = { bnn_w2, wt_bnn2, 128, 16, 18432, 0 };
  xa.j[6] = { bns_w1, wt_bns1, 128, 128, 147456, 0 };
  xa.j[7] = { bns_w2, wt_bns2, 128, 16, 18432, 0 };
  xa.j[8] = { d0_wc,  wt_d0c,  3, 3, 81, 0 };
  xa.j[9] = { d0_wt,  wd_dec,  128, 3, 6144, 1 };
  k_xform<<<dim3(576,10), 256, 0, stream>>>(xa);

  // encoder stems
  k_conv_cin3<16><<<4096, 256, 0, stream>>>(x, wt_e0n1, e0n_b1, t0);
  k_conv_cin3<128><<<32768, 256, 0, stream>>>(x, wt_e0s1, e0s_b1, t1);
  k_rowconv<16,16,2,128><<<512, 256, 0, stream>>>(t0, wt_e0n2, e0n_b2, e0n, nullptr, nullptr, 256, 256);
  k_rowconv<128,128,2,64><<<1024, 256, 0, stream>>>(t1, wt_e0s2, e0s_b2, e0s, nullptr, nullptr, 256, 256);

  // memcell 0 write
  k_weights<<<256, 256, 0, stream>>>(e0n, c0_zhat, w0T, nullptr, nullptr, T);
  k_gemm_out<128,false,false,false,false><<<1024, 256, 0, stream>>>(w0T, c0_That, nullptr, nullptr, read0, nullptr, T);
  k_delta<128><<<64, 256, 0, stream>>>(w0T, e0s, read0, delta0, T, 1024);
  k_gemm_out<128,true,true,true,false><<<1024, 256, 0, stream>>>(w0T, delta0, nullptr, read0, xt1, stats0, T);
  k_bnfin<<<1, 128, 0, stream>>>(stats0, g0, be0, sc0, sh0, 128, invT);

  // bottleneck branches (bn folded into input load)
  k_rowconv<128,128,1,128><<<512, 256, 0, stream>>>(xt1, wt_bnn1, bnn_b1, u1, sc0, sh0, 128, 128);
  k_rowconv<128,16,1,128><<<512, 256, 0, stream>>>(u1, wt_bnn2, bnn_b2, bnnb, nullptr, nullptr, 128, 128);
  k_rowconv<128,128,1,128><<<512, 256, 0, stream>>>(xt1, wt_bns1, bns_b1, u2, sc0, sh0, 128, 128);
  k_rowconv<128,16,1,128><<<512, 256, 0, stream>>>(u2, wt_bns2, bns_b2, bnsb, nullptr, nullptr, 128, 128);

  // memcell b write
  k_weights<<<256, 256, 0, stream>>>(bnnb, cb_zhat, wbT, nullptr, nullptr, T);
  k_gemm_out<16,false,false,false,false><<<512, 256, 0, stream>>>(wbT, cb_That, nullptr, nullptr, readb, nullptr, T);
  k_delta<16><<<64, 256, 0, stream>>>(wbT, bnsb, readb, deltab, T, 1024);
  k_gemm_out<16,true,true,true,false><<<512, 256, 0, stream>>>(wbT, deltab, nullptr, readb, xt2, statsb, T);
  k_bnfin<<<1, 64, 0, stream>>>(statsb, gb, bb, scb, shb, 16, invT);

  // decoder recall-read against cell 0
  k_weights<<<256, 256, 0, stream>>>(xt2, c0_zhat, w2T, scb, shb, T);
  k_gemm_out<128,false,true,true,true><<<1024, 256, 0, stream>>>(w2T, c0_That, delta0, nullptr, xt3, statsd, T);
  k_bnfin<<<1, 128, 0, stream>>>(statsd, gd, bd, scd, shd, 128, invT);

  // deconv + final conv
  k_deconv<<<1024, 256, 0, stream>>>(xt3, wd_dec, d0_bt, y1, scd, shd);
  k_conv33<<<1024, 256, 0, stream>>>(y1, wt_d0c, d0_bc, (float*)d_out);
}